// Round 8
// baseline (4406.629 us; speedup 1.0000x reference)
//
#include <hip/hip_runtime.h>
#include <hip/hip_bf16.h>
#include <math.h>

#define NN 100000
#define EE 1600000
#define DIN 384
#define HD 128
#define HHD 64
#define NRL 4
#define BN_EPS 1e-5f
#define NBUK 392  // dst buckets (dst>>8), 256 nodes each
#define EB 196    // edge chunks: 196*8192 >= EE
#define EPB 8192
#define XTILES ((NN + 63) / 64)   // 1563 input-projection / gemm tiles

typedef _Float16 half8 __attribute__((ext_vector_type(8)));
typedef float floatx4 __attribute__((ext_vector_type(4)));

// async global->LDS 16B: LDS dest = wave-uniform base + lane*16
__device__ __forceinline__ void async_cp16(const void* g, void* l) {
    __builtin_amdgcn_global_load_lds((const __attribute__((address_space(1))) void*)g,
                                     (__attribute__((address_space(3))) void*)l, 16, 0, 0);
}

// ---- one 64-row tile of h0 = relu(x @ Wp + bp), fp32 A via async LDS ----
__device__ __forceinline__ void gx_tile(const float* __restrict__ A,
                                        const _Float16* __restrict__ WpP,
                                        const float* __restrict__ bias,
                                        _Float16* __restrict__ C,
                                        float* __restrict__ As0, float* __restrict__ As1,
                                        int tile) {
    constexpr int K = DIN;
    constexpr int NC = K / 64;       // 6
    const int NT = 8;
    const int t = threadIdx.x;
    const int w = t >> 6;
    const int L = t & 63;
    const int q = L >> 4;
    const int l16 = L & 15;
    const int row0 = tile * 64;

    size_t gbase[4];
    float* lb0[4];
    float* lb1[4];
#pragma unroll
    for (int i = 0; i < 4; ++i) {
        int r = w * 16 + i * 4 + (L >> 4);
        int c = (L & 15) ^ (r & 15);
        gbase[i] = (size_t)min(row0 + r, NN - 1) * K + c * 4;
        lb0[i] = As0 + (w * 16 + i * 4) * 64;
        lb1[i] = As1 + (w * 16 + i * 4) * 64;
    }

    floatx4 acc[NT];
#pragma unroll
    for (int nt = 0; nt < NT; ++nt) acc[nt] = (floatx4){0.f, 0.f, 0.f, 0.f};

    const half8* __restrict__ bp8 = (const half8*)WpP;
    const int rr = w * 16 + l16;
    const int rbase = rr * 64;
    const int rx = rr & 15;

#pragma unroll
    for (int i = 0; i < 4; ++i) async_cp16(A + gbase[i], lb0[i]);
    __syncthreads();

    for (int kc = 0; kc < NC; ++kc) {
        if (kc + 1 < NC) {
            if ((kc & 1) == 0) {
#pragma unroll
                for (int i = 0; i < 4; ++i) async_cp16(A + gbase[i] + (kc + 1) * 64, lb1[i]);
            } else {
#pragma unroll
                for (int i = 0; i < 4; ++i) async_cp16(A + gbase[i] + (kc + 1) * 64, lb0[i]);
            }
        }
        const float* cur = (kc & 1) ? As1 : As0;
#pragma unroll
        for (int kk = 0; kk < 2; ++kk) {
            int cb = kk * 8 + 2 * q;
            float4 f0 = *(const float4*)(cur + rbase + ((cb ^ rx) * 4));
            float4 f1 = *(const float4*)(cur + rbase + (((cb + 1) ^ rx) * 4));
            half8 a = {(_Float16)f0.x, (_Float16)f0.y, (_Float16)f0.z, (_Float16)f0.w,
                       (_Float16)f1.x, (_Float16)f1.y, (_Float16)f1.z, (_Float16)f1.w};
#pragma unroll
            for (int nt = 0; nt < NT; ++nt) {
                half8 b = bp8[(size_t)((kc * 2 + kk) * NT + nt) * 64 + L];
                acc[nt] = __builtin_amdgcn_mfma_f32_16x16x32_f16(a, b, acc[nt], 0, 0, 0);
            }
        }
        __syncthreads();
    }

#pragma unroll
    for (int r = 0; r < 4; ++r) {
        int row = row0 + w * 16 + q * 4 + r;
        if (row >= NN) continue;
#pragma unroll
        for (int nt = 0; nt < NT; ++nt) {
            int c = nt * 16 + l16;
            C[(size_t)row * HD + c] = (_Float16)fmaxf(acc[nt][r] + bias[c], 0.f);
        }
    }
}

// ---- K1: histb (blocks 0..EB) || weight pack (remaining blocks) ----
#define PKB 96
__global__ __launch_bounds__(256) void hist_pack_k(
        const int* __restrict__ dst, int* __restrict__ blockHist,
        const float* __restrict__ Wp, const float* __restrict__ Wc,
        const float* __restrict__ relW1, const float* __restrict__ rsW1, const float* __restrict__ rlW1,
        const float* __restrict__ relb1, const float* __restrict__ rsb1, const float* __restrict__ rlb1,
        _Float16* __restrict__ WpP, _Float16* __restrict__ WcP,
        _Float16* __restrict__ W1P, float* __restrict__ b1p) {
    __shared__ int h[NBUK];
    const int bid = blockIdx.x;
    const int t = threadIdx.x;
    if (bid < EB) {
        for (int i = t; i < NBUK; i += 256) h[i] = 0;
        __syncthreads();
        int base = bid * EPB;
#pragma unroll
        for (int i = 0; i < 32; ++i) {
            int e = base + i * 256 + t;
            if (e < EE) atomicAdd(&h[dst[e] >> 8], 1);
        }
        __syncthreads();
        for (int i = t; i < NBUK; i += 256) blockHist[i * EB + bid] = h[i];
    } else {
        const int gb = bid - EB;
        for (int u = gb * 256 + t; u < DIN * HD + 3 * HD * HD; u += PKB * 256) {
            const float* B;
            _Float16* out;
            int idx;
            if (u < DIN * HD) { B = Wp; out = WpP; idx = u; }
            else {
                int r = u - DIN * HD;
                int layer = r / (HD * HD);
                idx = r - layer * HD * HD;
                B = Wc + (size_t)layer * HD * HD;
                out = WcP + (size_t)layer * HD * HD;
            }
            int j = idx & 7;
            int ln = (idx >> 3) & 63;
            int rest = idx >> 9;
            int nt = rest % 8;
            int kc = rest / 8;
            int k = kc * 32 + (ln >> 4) * 8 + j;
            int c = nt * 16 + (ln & 15);
            out[idx] = (_Float16)B[(size_t)k * HD + c];
        }
        for (int u = gb * 256 + t; u < HD * 192; u += PKB * 256) {
            int j = u & 7;
            int ln = (u >> 3) & 63;
            int rest = u >> 9;
            int nt = rest % 12;
            int kc = rest / 12;
            int k = kc * 32 + (ln >> 4) * 8 + j;
            int c = nt * 16 + (ln & 15);
            int s = c >> 6, jj = c & 63;
            float v = (s == 0) ? relW1[k * HHD + jj] : (s == 1) ? rsW1[k * HHD + jj] : rlW1[k * HHD + jj];
            W1P[u] = (_Float16)v;
        }
        if (gb == 0 && t < 192) {
            int s = t >> 6, jj = t & 63;
            b1p[t] = (s == 0) ? relb1[jj] : (s == 1) ? rsb1[jj] : rlb1[jj];
        }
    }
}

// ---- K2: per-bucket scan of eHist rows (blocks 0..NBUK) || tiles [0,521) ----
#define T2N 521
__global__ __launch_bounds__(256) void escan_gx_k(
        const int* __restrict__ eHist, int* __restrict__ ebaseL, int* __restrict__ bktTot,
        const float* __restrict__ x, const _Float16* __restrict__ WpP,
        const float* __restrict__ bp, _Float16* __restrict__ h0) {
    __shared__ union { float asx[2][64 * 64]; int sW[4]; } sm;
    const int bid = blockIdx.x;
    const int t = threadIdx.x;
    if (bid < NBUK) {
        int lane = t & 63, wid = t >> 6;
        int v = (t < EB) ? eHist[bid * EB + t] : 0;
        int xx = v;
#pragma unroll
        for (int off = 1; off < 64; off <<= 1) {
            int y = __shfl_up(xx, off, 64);
            if (lane >= off) xx += y;
        }
        if (lane == 63) sm.sW[wid] = xx;
        __syncthreads();
        if (t == 0) {
            int run = 0;
#pragma unroll
            for (int i = 0; i < 4; ++i) { int c = sm.sW[i]; sm.sW[i] = run; run += c; }
        }
        __syncthreads();
        int excl = xx - v + sm.sW[wid];
        if (t < EB) ebaseL[bid * EB + t] = excl;
        if (t == 255) bktTot[bid] = excl;
    } else {
        gx_tile(x, WpP, bp, h0, sm.asx[0], sm.asx[1], bid - NBUK);
    }
}

// in-block exclusive scan of bktTot[0..NBUK) -> sBo[0..NBUK], sBo[NBUK]=EE
__device__ __forceinline__ void bo_scan(const int* __restrict__ bktTot, int* sBo, int* sW) {
    const int t = threadIdx.x;
    const int lane = t & 63, wid = t >> 6;
    int i0 = 2 * t, i1 = 2 * t + 1;
    int v0 = (i0 < NBUK) ? bktTot[i0] : 0;
    int v1 = (i1 < NBUK) ? bktTot[i1] : 0;
    int s = v0 + v1;
    int xx = s;
#pragma unroll
    for (int off = 1; off < 64; off <<= 1) {
        int y = __shfl_up(xx, off, 64);
        if (lane >= off) xx += y;
    }
    if (lane == 63) sW[wid] = xx;
    __syncthreads();
    if (t == 0) {
        int run = 0;
#pragma unroll
        for (int i = 0; i < 4; ++i) { int c = sW[i]; sW[i] = run; run += c; }
    }
    __syncthreads();
    int excl = xx - s + sW[wid];
    if (i0 < NBUK) sBo[i0] = excl;
    if (i1 < NBUK) sBo[i1] = excl + v0;
    if (t == 0) sBo[NBUK] = EE;
    __syncthreads();
}

// ---- K3: ebfill (blocks 0..EB, with in-block bo scan) || tiles [521,1042) ----
#define T3N 521
__global__ __launch_bounds__(256) void ebfill_gx_k(
        const int* __restrict__ src, const int* __restrict__ dst,
        const int* __restrict__ ebaseL, const int* __restrict__ bktTot,
        unsigned* __restrict__ ebuf,
        const float* __restrict__ x, const _Float16* __restrict__ WpP,
        const float* __restrict__ bp, _Float16* __restrict__ h0) {
    __shared__ union {
        float asx[2][64 * 64];
        struct { int sBo[NBUK + 1]; int sH[NBUK]; int sW[4]; } c;
    } sm;
    const int bid = blockIdx.x;
    const int t = threadIdx.x;
    if (bid < EB) {
        bo_scan(bktTot, sm.c.sBo, sm.c.sW);
        for (int i = t; i < NBUK; i += 256) sm.c.sH[i] = sm.c.sBo[i] + ebaseL[i * EB + bid];
        __syncthreads();
        int base = bid * EPB;
#pragma unroll
        for (int i = 0; i < 32; ++i) {
            int e = base + i * 256 + t;
            if (e < EE) {
                unsigned sv = (unsigned)src[e], d = (unsigned)dst[e];
                int p = atomicAdd(&sm.c.sH[d >> 8], 1);
                ebuf[p] = (sv << 8) | (d & 255u);
            }
        }
    } else {
        gx_tile(x, WpP, bp, h0, sm.asx[0], sm.asx[1], T2N + bid - EB);
    }
}

// ---- K4: per-bucket counting sort by src>>9 (coarse src windows) -> ebuf2, + dinv ----
// Gives each bucket's edge stream ascending-src-window order so that agg2's 784
// blocks sweep src memory in chip-wide near-lockstep (L2-resident window).
// Replaces cfill/col/perm/counting-sort entirely.
#define T4N (XTILES - T2N - T3N)   // 521
__global__ __launch_bounds__(256) void esort_gx_k(
        const unsigned* __restrict__ ebuf, const int* __restrict__ bktTot,
        unsigned* __restrict__ ebuf2, float* __restrict__ dinv,
        const float* __restrict__ x, const _Float16* __restrict__ WpP,
        const float* __restrict__ bp, _Float16* __restrict__ h0) {
    __shared__ union {
        float asx[2][64 * 64];
        struct { int sBo[NBUK + 1]; int hist[256]; int dlh[256]; int binOff[256]; int sW[4]; } c;
    } sm;
    const int bid = blockIdx.x;
    const int t = threadIdx.x;
    if (bid < NBUK) {
        bo_scan(bktTot, sm.c.sBo, sm.c.sW);
        const int b = bid;
        const int lo = sm.c.sBo[b], hi = sm.c.sBo[b + 1];
        sm.c.hist[t] = 0;
        sm.c.dlh[t] = 0;
        __syncthreads();
        for (int j = lo + t; j < hi; j += 256) {
            unsigned u = ebuf[j];
            atomicAdd(&sm.c.hist[u >> 17], 1);    // src>>9, max 195
            atomicAdd(&sm.c.dlh[u & 255u], 1);
        }
        __syncthreads();
        int v = sm.c.hist[t];
        int lane = t & 63, wid = t >> 6;
        int xx = v;
#pragma unroll
        for (int off = 1; off < 64; off <<= 1) {
            int y = __shfl_up(xx, off, 64);
            if (lane >= off) xx += y;
        }
        if (lane == 63) sm.c.sW[wid] = xx;
        __syncthreads();
        if (t == 0) {
            int run = 0;
#pragma unroll
            for (int i = 0; i < 4; ++i) { int c = sm.c.sW[i]; sm.c.sW[i] = run; run += c; }
        }
        __syncthreads();
        sm.c.binOff[t] = lo + xx - v + sm.c.sW[wid];
        int node = (b << 8) + t;
        if (node < NN) dinv[node] = rsqrtf((float)sm.c.dlh[t] + 1.0f);
        __syncthreads();
        for (int j = lo + t; j < hi; j += 256) {
            unsigned u = ebuf[j];
            int p = atomicAdd(&sm.c.binOff[u >> 17], 1);
            ebuf2[p] = u;
        }
    } else {
        gx_tile(x, WpP, bp, h0, sm.asx[0], sm.asx[1], T2N + T3N + bid - NBUK);
    }
}

// ---------------- MFMA GEMM (fp16 A) with async-LDS double buffer ----------------
template<int K, int MODE>
__global__ __launch_bounds__(256) void mgemm2_k(const _Float16* __restrict__ A,
                                                const _Float16* __restrict__ Bp,
                                                const float* __restrict__ bias,
                                                const float* __restrict__ dinv,
                                                _Float16* __restrict__ C) {
    constexpr int NC = K / 64;
    const int NT = 8;
    __shared__ _Float16 As[2][64 * 64];
    const int tid = threadIdx.x;
    const int w = tid >> 6;
    const int L = tid & 63;
    const int q = L >> 4;
    const int l16 = L & 15;
    const int row0 = blockIdx.x * 64;

    const int r8 = L >> 3;
    const int scol = ((L & 7) ^ r8) * 8;
    const size_t srow0 = (size_t)min(row0 + w * 8 + r8, NN - 1) * K;
    const size_t srow1 = (size_t)min(row0 + 32 + w * 8 + r8, NN - 1) * K;
    _Float16* lds0a = &As[0][w * 512];
    _Float16* lds0b = &As[0][(4 + w) * 512];
    _Float16* lds1a = &As[1][w * 512];
    _Float16* lds1b = &As[1][(4 + w) * 512];

    floatx4 acc[NT];
#pragma unroll
    for (int nt = 0; nt < NT; ++nt) acc[nt] = (floatx4){0.f, 0.f, 0.f, 0.f};

    const half8* __restrict__ bp8 = (const half8*)Bp;
    const int rs = l16 & 7;
    const int gsel = (w * 2 + (l16 >> 3)) * 512 + rs * 64;

    async_cp16(A + srow0 + scol, lds0a);
    async_cp16(A + srow1 + scol, lds0b);
    __syncthreads();

    for (int kc = 0; kc < NC; ++kc) {
        if (kc + 1 < NC) {
            if ((kc & 1) == 0) {
                async_cp16(A + srow0 + (kc + 1) * 64 + scol, lds1a);
                async_cp16(A + srow1 + (kc + 1) * 64 + scol, lds1b);
            } else {
                async_cp16(A + srow0 + (kc + 1) * 64 + scol, lds0a);
                async_cp16(A + srow1 + (kc + 1) * 64 + scol, lds0b);
            }
        }
        const _Float16* cur = As[kc & 1];
#pragma unroll
        for (int kk = 0; kk < 2; ++kk) {
            int chunk = kk * 4 + q;
            half8 a = *(const half8*)(cur + gsel + ((chunk ^ rs) * 8));
#pragma unroll
            for (int nt = 0; nt < NT; ++nt) {
                half8 b = bp8[(size_t)((kc * 2 + kk) * NT + nt) * 64 + L];
                acc[nt] = __builtin_amdgcn_mfma_f32_16x16x32_f16(a, b, acc[nt], 0, 0, 0);
            }
        }
        __syncthreads();
    }

#pragma unroll
    for (int r = 0; r < 4; ++r) {
        int row = row0 + w * 16 + q * 4 + r;
        if (row >= NN) continue;
        if (MODE == 0) {
#pragma unroll
            for (int nt = 0; nt < NT; ++nt) {
                int c = nt * 16 + l16;
                C[(size_t)row * HD + c] = (_Float16)fmaxf(acc[nt][r] + bias[c], 0.f);
            }
        } else {
            float dv = dinv[row];
#pragma unroll
            for (int nt = 0; nt < NT; ++nt) {
                int c = nt * 16 + l16;
                C[(size_t)row * HD + c] = (_Float16)(acc[nt][r] * dv);
            }
        }
    }
}

// ---------------- bucket-major aggregation: LDS accum + src-sweep gather ----------------
// 2 blocks per bucket (half = 128 dst nodes each); both stream the bucket's
// src-sorted edges (ebuf2) and commit only their half -> all 784 blocks sweep
// hws in ascending src order together (L2-resident window). fp32 LDS accum.
__global__ __launch_bounds__(256) void agg2_k(const _Float16* __restrict__ hws,
                                              const _Float16* __restrict__ h_in,
                                              _Float16* __restrict__ h_out,
                                              const float* __restrict__ dinv,
                                              const int* __restrict__ bktTot,
                                              const unsigned* __restrict__ eb2,
                                              const float* __restrict__ bcv,
                                              const float* __restrict__ gamma,
                                              const float* __restrict__ beta,
                                              const float* __restrict__ rmean,
                                              const float* __restrict__ rvar,
                                              int residual) {
    __shared__ float accum[128 * HD];   // 64 KB
    __shared__ int sBo[NBUK + 1];
    __shared__ int sW[4];
    bo_scan(bktTot, sBo, sW);
    const int t = threadIdx.x;
    const int b = blockIdx.x >> 1;
    const unsigned hsel = blockIdx.x & 1;
    const int lo = sBo[b], hi = sBo[b + 1];
    const int nodeBase = (b << 8) + (int)hsel * 128;

    for (int i = t; i < 128 * HD; i += 256) accum[i] = 0.f;
    __syncthreads();

    const int g = t >> 4, l = t & 15, f0 = l * 8;

    for (int jj = lo + g; jj < hi; jj += 32) {
        unsigned u0 = eb2[jj];
        int j1 = jj + 16;
        unsigned u1 = (j1 < hi) ? eb2[j1] : 0u;
        bool p0 = ((u0 >> 7) & 1u) == hsel;
        bool p1 = (j1 < hi) && (((u1 >> 7) & 1u) == hsel);
        half8 v0, v1;
        if (p0) v0 = *(const half8*)(hws + (size_t)(u0 >> 8) * HD + f0);
        if (p1) v1 = *(const half8*)(hws + (size_t)(u1 >> 8) * HD + f0);
        if (p0) {
            float* ap = &accum[(int)(u0 & 127u) * HD + f0];
#pragma unroll
            for (int i = 0; i < 8; ++i) atomicAdd(&ap[i], (float)v0[i]);
        }
        if (p1) {
            float* ap = &accum[(int)(u1 & 127u) * HD + f0];
#pragma unroll
            for (int i = 0; i < 8; ++i) atomicAdd(&ap[i], (float)v1[i]);
        }
    }
    __syncthreads();

    // per-lane BN constants (feature slice fixed per lane)
    float scl[8], sft[8], bcl[8];
#pragma unroll
    for (int i = 0; i < 8; ++i) {
        int f = f0 + i;
        scl[i] = gamma[f] * rsqrtf(rvar[f] + BN_EPS);
        sft[i] = beta[f] - rmean[f] * scl[i];
        bcl[i] = bcv[f];
    }

#pragma unroll
    for (int k = 0; k < 8; ++k) {
        int dl2 = k * 16 + g;
        int node = nodeBase + dl2;
        if (node >= NN) continue;
        float dv = dinv[node];
        half8 vself = *(const half8*)(hws + (size_t)node * HD + f0);
        half8 hin;
        if (residual) hin = *(const half8*)(h_in + (size_t)node * HD + f0);
        half8 outv;
#pragma unroll
        for (int i = 0; i < 8; ++i) {
            float pre = dv * (accum[dl2 * HD + f0 + i] + (float)vself[i]) + bcl[i];
            float vv = pre * scl[i] + sft[i];
            vv = fmaxf(vv, 0.f);
            if (residual) vv += (float)hin[i];
            outv[i] = (_Float16)vv;
        }
        *(half8*)(h_out + (size_t)node * HD + f0) = outv;
    }
}

// ---------------- fused heads ----------------
__global__ __launch_bounds__(256) void heads_k(const _Float16* __restrict__ hfin,
                                               const _Float16* __restrict__ W1P,
                                               const float* __restrict__ b1p,
                                               const float* __restrict__ relW2, const float* __restrict__ relb2,
                                               const float* __restrict__ rsW2,  const float* __restrict__ rsb2,
                                               const float* __restrict__ rlW2,  const float* __restrict__ rlb2,
                                               float* __restrict__ out) {
    __shared__ float Hs[64 * 196];
#define HS(r, c) Hs[(r) * 196 + (c)]
    const int NT = 12;
    const int tid = threadIdx.x;
    const int w = tid >> 6;
    const int L = tid & 63;
    const int q = L >> 4;
    const int l16 = L & 15;
    const int row0 = blockIdx.x * 64 + w * 16;

    floatx4 acc[NT];
#pragma unroll
    for (int nt = 0; nt < NT; ++nt) acc[nt] = (floatx4){0.f, 0.f, 0.f, 0.f};

    const half8* __restrict__ bp8 = (const half8*)W1P;
    const half8 hz = {(_Float16)0, (_Float16)0, (_Float16)0, (_Float16)0,
                      (_Float16)0, (_Float16)0, (_Float16)0, (_Float16)0};
    const int r0 = row0 + l16;

#pragma unroll
    for (int kc = 0; kc < HD / 32; ++kc) {
        half8 a = (r0 < NN) ? *(const half8*)(hfin + (size_t)r0 * HD + kc * 32 + q * 8) : hz;
#pragma unroll
        for (int nt = 0; nt < NT; ++nt) {
            half8 b = bp8[(size_t)(kc * NT + nt) * 64 + L];
            acc[nt] = __builtin_amdgcn_mfma_f32_16x16x32_f16(a, b, acc[nt], 0, 0, 0);
        }
    }

#pragma unroll
    for (int nt = 0; nt < NT; ++nt) {
        int c = nt * 16 + l16;
        float bb = b1p[c];
#pragma unroll
        for (int r = 0; r < 4; ++r)
            HS(w * 16 + q * 4 + r, c) = fmaxf(acc[nt][r] + bb, 0.f);
    }
    __syncthreads();

    for (int t = tid; t < 64 * 6; t += 256) {
        int row = t & 63;
        int o = t >> 6;
        int grow = blockIdx.x * 64 + row;
        if (grow >= NN) continue;
        if (o == 0) {
            float s = 0.f;
#pragma unroll
            for (int jj = 0; jj < 64; ++jj) s += HS(row, 64 + jj) * rsW2[jj];
            out[grow] = 1.f / (1.f + expf(-(s + rsb2[0])));
        } else if (o <= 4) {
            int c = o - 1;
            float s = 0.f;
#pragma unroll
            for (int jj = 0; jj < 64; ++jj) s += HS(row, 128 + jj) * rlW2[jj * NRL + c];
            out[NN + (size_t)grow * NRL + c] = s + rlb2[c];
        } else {
            float s = 0.f;
#pragma unroll
            for (int jj = 0; jj < 64; ++jj) s += HS(row, jj) * relW2[jj];
            out[NN * (1 + NRL) + grow] = 1.f / (1.f + expf(-(s + relb2[0])));
        }
    }
#undef HS
}

extern "C" void kernel_launch(void* const* d_in, const int* in_sizes, int n_in,
                              void* d_out, int out_size, void* d_ws, size_t ws_size,
                              hipStream_t stream) {
    const float* x     = (const float*)d_in[0];
    const int*   ei    = (const int*)d_in[1];
    const float* Wp    = (const float*)d_in[2];
    const float* bp    = (const float*)d_in[3];
    const float* Wc    = (const float*)d_in[4];
    const float* bc    = (const float*)d_in[5];
    const float* gamma = (const float*)d_in[6];
    const float* beta  = (const float*)d_in[7];
    const float* rmean = (const float*)d_in[8];
    const float* rvar  = (const float*)d_in[9];
    const float* relW1 = (const float*)d_in[10];
    const float* relb1 = (const float*)d_in[11];
    const float* relW2 = (const float*)d_in[12];
    const float* relb2 = (const float*)d_in[13];
    const float* rsW1  = (const float*)d_in[14];
    const float* rsb1  = (const float*)d_in[15];
    const float* rsW2  = (const float*)d_in[16];
    const float* rsb2  = (const float*)d_in[17];
    const float* rlW1  = (const float*)d_in[18];
    const float* rlb1  = (const float*)d_in[19];
    const float* rlW2  = (const float*)d_in[20];
    const float* rlb2  = (const float*)d_in[21];
    float* out = (float*)d_out;

    char* w = (char*)d_ws;
    _Float16* h0  = (_Float16*)w; w += (size_t)NN * HD * 2;
    _Float16* h1  = (_Float16*)w; w += (size_t)NN * HD * 2;
    _Float16* hws = (_Float16*)w; w += (size_t)NN * HD * 2;
    _Float16* WpP = (_Float16*)w; w += (size_t)DIN * HD * 2;
    _Float16* WcP = (_Float16*)w; w += (size_t)3 * HD * HD * 2;
    _Float16* W1P = (_Float16*)w; w += (size_t)HD * 192 * 2;
    float* b1p    = (float*)w;    w += 256 * 4;
    float* dinv   = (float*)w;    w += (size_t)NN * 4;
    int* eHist    = (int*)w;      w += (size_t)NBUK * EB * 4;
    int* ebaseL   = (int*)w;      w += (size_t)(NBUK * EB + 4) * 4;
    int* bktTot   = (int*)w;      w += (size_t)(NBUK + 4) * 4;
    w = (char*)(((size_t)w + 255) & ~(size_t)255);
    unsigned* ebuf = (unsigned*)w;  w += (size_t)EE * 4;
    w = (char*)(((size_t)w + 255) & ~(size_t)255);
    unsigned* ebuf2 = (unsigned*)w; w += (size_t)EE * 4;

    const int* srcIdx = ei;
    const int* dstIdx = ei + EE;

    // front-end: CSR-free edge pipeline (phase per launch) || pack + input projection
    hist_pack_k<<<EB + PKB, 256, 0, stream>>>(dstIdx, eHist, Wp, Wc,
                                              relW1, rsW1, rlW1, relb1, rsb1, rlb1,
                                              WpP, WcP, W1P, b1p);
    escan_gx_k<<<NBUK + T2N, 256, 0, stream>>>(eHist, ebaseL, bktTot, x, WpP, bp, h0);
    ebfill_gx_k<<<EB + T3N, 256, 0, stream>>>(srcIdx, dstIdx, ebaseL, bktTot, ebuf,
                                              x, WpP, bp, h0);
    esort_gx_k<<<NBUK + T4N, 256, 0, stream>>>(ebuf, bktTot, ebuf2, dinv,
                                               x, WpP, bp, h0);

    const int gemmGrid = (NN + 63) / 64;
    const int aggGrid = NBUK * 2;

    // layer 0
    mgemm2_k<HD, 1><<<gemmGrid, 256, 0, stream>>>(h0, WcP + 0 * HD * HD, nullptr, dinv, hws);
    agg2_k<<<aggGrid, 256, 0, stream>>>(hws, h0, h1, dinv, bktTot, ebuf2,
                                        bc + 0 * HD, gamma + 0 * HD, beta + 0 * HD,
                                        rmean + 0 * HD, rvar + 0 * HD, 0);
    // layer 1
    mgemm2_k<HD, 1><<<gemmGrid, 256, 0, stream>>>(h1, WcP + 1 * HD * HD, nullptr, dinv, hws);
    agg2_k<<<aggGrid, 256, 0, stream>>>(hws, h1, h0, dinv, bktTot, ebuf2,
                                        bc + 1 * HD, gamma + 1 * HD, beta + 1 * HD,
                                        rmean + 1 * HD, rvar + 1 * HD, 1);
    // layer 2
    mgemm2_k<HD, 1><<<gemmGrid, 256, 0, stream>>>(h0, WcP + 2 * HD * HD, nullptr, dinv, hws);
    agg2_k<<<aggGrid, 256, 0, stream>>>(hws, h0, h1, dinv, bktTot, ebuf2,
                                        bc + 2 * HD, gamma + 2 * HD, beta + 2 * HD,
                                        rmean + 2 * HD, rvar + 2 * HD, 1);

    // heads
    heads_k<<<(NN + 63) / 64, 256, 0, stream>>>(h1, W1P, b1p, relW2, relb2, rsW2, rsb2, rlW2, rlb2, out);
}

// Round 9
// 605.031 us; speedup vs baseline: 7.2833x; 7.2833x over previous
//
#include <hip/hip_runtime.h>
#include <hip/hip_bf16.h>
#include <math.h>

#define NN 100000
#define EE 1600000
#define DIN 384
#define HD 128
#define HHD 64
#define NRL 4
#define BN_EPS 1e-5f
#define NBUK 392  // dst buckets (dst>>8), 256 nodes each
#define EB 196    // edge chunks: 196*8192 >= EE
#define EPB 8192
#define XTILES ((NN + 63) / 64)   // 1563 input-projection / gemm tiles

typedef _Float16 half8 __attribute__((ext_vector_type(8)));
typedef float floatx4 __attribute__((ext_vector_type(4)));

// async global->LDS 16B: LDS dest = wave-uniform base + lane*16
__device__ __forceinline__ void async_cp16(const void* g, void* l) {
    __builtin_amdgcn_global_load_lds((const __attribute__((address_space(1))) void*)g,
                                     (__attribute__((address_space(3))) void*)l, 16, 0, 0);
}

// ---- one 64-row tile of h0 = relu(x @ Wp + bp), fp32 A via async LDS ----
__device__ __forceinline__ void gx_tile(const float* __restrict__ A,
                                        const _Float16* __restrict__ WpP,
                                        const float* __restrict__ bias,
                                        _Float16* __restrict__ C,
                                        float* __restrict__ As0, float* __restrict__ As1,
                                        int tile) {
    constexpr int K = DIN;
    constexpr int NC = K / 64;       // 6
    const int NT = 8;
    const int t = threadIdx.x;
    const int w = t >> 6;
    const int L = t & 63;
    const int q = L >> 4;
    const int l16 = L & 15;
    const int row0 = tile * 64;

    size_t gbase[4];
    float* lb0[4];
    float* lb1[4];
#pragma unroll
    for (int i = 0; i < 4; ++i) {
        int r = w * 16 + i * 4 + (L >> 4);
        int c = (L & 15) ^ (r & 15);
        gbase[i] = (size_t)min(row0 + r, NN - 1) * K + c * 4;
        lb0[i] = As0 + (w * 16 + i * 4) * 64;
        lb1[i] = As1 + (w * 16 + i * 4) * 64;
    }

    floatx4 acc[NT];
#pragma unroll
    for (int nt = 0; nt < NT; ++nt) acc[nt] = (floatx4){0.f, 0.f, 0.f, 0.f};

    const half8* __restrict__ bp8 = (const half8*)WpP;
    const int rr = w * 16 + l16;
    const int rbase = rr * 64;
    const int rx = rr & 15;

#pragma unroll
    for (int i = 0; i < 4; ++i) async_cp16(A + gbase[i], lb0[i]);
    __syncthreads();

    for (int kc = 0; kc < NC; ++kc) {
        if (kc + 1 < NC) {
            if ((kc & 1) == 0) {
#pragma unroll
                for (int i = 0; i < 4; ++i) async_cp16(A + gbase[i] + (kc + 1) * 64, lb1[i]);
            } else {
#pragma unroll
                for (int i = 0; i < 4; ++i) async_cp16(A + gbase[i] + (kc + 1) * 64, lb0[i]);
            }
        }
        const float* cur = (kc & 1) ? As1 : As0;
#pragma unroll
        for (int kk = 0; kk < 2; ++kk) {
            int cb = kk * 8 + 2 * q;
            float4 f0 = *(const float4*)(cur + rbase + ((cb ^ rx) * 4));
            float4 f1 = *(const float4*)(cur + rbase + (((cb + 1) ^ rx) * 4));
            half8 a = {(_Float16)f0.x, (_Float16)f0.y, (_Float16)f0.z, (_Float16)f0.w,
                       (_Float16)f1.x, (_Float16)f1.y, (_Float16)f1.z, (_Float16)f1.w};
#pragma unroll
            for (int nt = 0; nt < NT; ++nt) {
                half8 b = bp8[(size_t)((kc * 2 + kk) * NT + nt) * 64 + L];
                acc[nt] = __builtin_amdgcn_mfma_f32_16x16x32_f16(a, b, acc[nt], 0, 0, 0);
            }
        }
        __syncthreads();
    }

#pragma unroll
    for (int r = 0; r < 4; ++r) {
        int row = row0 + w * 16 + q * 4 + r;
        if (row >= NN) continue;
#pragma unroll
        for (int nt = 0; nt < NT; ++nt) {
            int c = nt * 16 + l16;
            C[(size_t)row * HD + c] = (_Float16)fmaxf(acc[nt][r] + bias[c], 0.f);
        }
    }
}

// ---- K1: histb (blocks 0..EB) || weight pack (remaining blocks) ----
#define PKB 96
__global__ __launch_bounds__(256) void hist_pack_k(
        const int* __restrict__ dst, int* __restrict__ blockHist,
        const float* __restrict__ Wp, const float* __restrict__ Wc,
        const float* __restrict__ relW1, const float* __restrict__ rsW1, const float* __restrict__ rlW1,
        const float* __restrict__ relb1, const float* __restrict__ rsb1, const float* __restrict__ rlb1,
        _Float16* __restrict__ WpP, _Float16* __restrict__ WcP,
        _Float16* __restrict__ W1P, float* __restrict__ b1p) {
    __shared__ int h[NBUK];
    const int bid = blockIdx.x;
    const int t = threadIdx.x;
    if (bid < EB) {
        for (int i = t; i < NBUK; i += 256) h[i] = 0;
        __syncthreads();
        int base = bid * EPB;
#pragma unroll
        for (int i = 0; i < 32; ++i) {
            int e = base + i * 256 + t;
            if (e < EE) atomicAdd(&h[dst[e] >> 8], 1);
        }
        __syncthreads();
        for (int i = t; i < NBUK; i += 256) blockHist[i * EB + bid] = h[i];
    } else {
        const int gb = bid - EB;
        for (int u = gb * 256 + t; u < DIN * HD + 3 * HD * HD; u += PKB * 256) {
            const float* B;
            _Float16* out;
            int idx;
            if (u < DIN * HD) { B = Wp; out = WpP; idx = u; }
            else {
                int r = u - DIN * HD;
                int layer = r / (HD * HD);
                idx = r - layer * HD * HD;
                B = Wc + (size_t)layer * HD * HD;
                out = WcP + (size_t)layer * HD * HD;
            }
            int j = idx & 7;
            int ln = (idx >> 3) & 63;
            int rest = idx >> 9;
            int nt = rest % 8;
            int kc = rest / 8;
            int k = kc * 32 + (ln >> 4) * 8 + j;
            int c = nt * 16 + (ln & 15);
            out[idx] = (_Float16)B[(size_t)k * HD + c];
        }
        for (int u = gb * 256 + t; u < HD * 192; u += PKB * 256) {
            int j = u & 7;
            int ln = (u >> 3) & 63;
            int rest = u >> 9;
            int nt = rest % 12;
            int kc = rest / 12;
            int k = kc * 32 + (ln >> 4) * 8 + j;
            int c = nt * 16 + (ln & 15);
            int s = c >> 6, jj = c & 63;
            float v = (s == 0) ? relW1[k * HHD + jj] : (s == 1) ? rsW1[k * HHD + jj] : rlW1[k * HHD + jj];
            W1P[u] = (_Float16)v;
        }
        if (gb == 0 && t < 192) {
            int s = t >> 6, jj = t & 63;
            b1p[t] = (s == 0) ? relb1[jj] : (s == 1) ? rsb1[jj] : rlb1[jj];
        }
    }
}

// ---- K2: per-bucket scan of eHist rows (blocks 0..NBUK) || tiles [0,384) ----
#define T2N 384
__global__ __launch_bounds__(256) void escan_gx_k(
        const int* __restrict__ eHist, int* __restrict__ ebaseL, int* __restrict__ bktTot,
        const float* __restrict__ x, const _Float16* __restrict__ WpP,
        const float* __restrict__ bp, _Float16* __restrict__ h0) {
    __shared__ union { float asx[2][64 * 64]; int sW[4]; } sm;
    const int bid = blockIdx.x;
    const int t = threadIdx.x;
    if (bid < NBUK) {
        int lane = t & 63, wid = t >> 6;
        int v = (t < EB) ? eHist[bid * EB + t] : 0;
        int xx = v;
#pragma unroll
        for (int off = 1; off < 64; off <<= 1) {
            int y = __shfl_up(xx, off, 64);
            if (lane >= off) xx += y;
        }
        if (lane == 63) sm.sW[wid] = xx;
        __syncthreads();
        if (t == 0) {
            int run = 0;
#pragma unroll
            for (int i = 0; i < 4; ++i) { int c = sm.sW[i]; sm.sW[i] = run; run += c; }
        }
        __syncthreads();
        int excl = xx - v + sm.sW[wid];
        if (t < EB) ebaseL[bid * EB + t] = excl;
        if (t == 255) bktTot[bid] = excl;
    } else {
        gx_tile(x, WpP, bp, h0, sm.asx[0], sm.asx[1], bid - NBUK);
    }
}

// in-block exclusive scan of bktTot[0..NBUK) -> sBo[0..NBUK], sBo[NBUK]=EE
__device__ __forceinline__ void bo_scan(const int* __restrict__ bktTot, int* sBo, int* sW) {
    const int t = threadIdx.x;
    const int lane = t & 63, wid = t >> 6;
    int i0 = 2 * t, i1 = 2 * t + 1;
    int v0 = (i0 < NBUK) ? bktTot[i0] : 0;
    int v1 = (i1 < NBUK) ? bktTot[i1] : 0;
    int s = v0 + v1;
    int xx = s;
#pragma unroll
    for (int off = 1; off < 64; off <<= 1) {
        int y = __shfl_up(xx, off, 64);
        if (lane >= off) xx += y;
    }
    if (lane == 63) sW[wid] = xx;
    __syncthreads();
    if (t == 0) {
        int run = 0;
#pragma unroll
        for (int i = 0; i < 4; ++i) { int c = sW[i]; sW[i] = run; run += c; }
    }
    __syncthreads();
    int excl = xx - s + sW[wid];
    if (i0 < NBUK) sBo[i0] = excl;
    if (i1 < NBUK) sBo[i1] = excl + v0;
    if (t == 0) sBo[NBUK] = EE;
    __syncthreads();
}

// ---- K3: ebfill (blocks 0..EB, with in-block bo scan) || tiles [384,768) ----
#define T3N 384
__global__ __launch_bounds__(256) void ebfill_gx_k(
        const int* __restrict__ src, const int* __restrict__ dst,
        const int* __restrict__ ebaseL, const int* __restrict__ bktTot,
        unsigned* __restrict__ ebuf,
        const float* __restrict__ x, const _Float16* __restrict__ WpP,
        const float* __restrict__ bp, _Float16* __restrict__ h0) {
    __shared__ union {
        float asx[2][64 * 64];
        struct { int sBo[NBUK + 1]; int sH[NBUK]; int sW[4]; } c;
    } sm;
    const int bid = blockIdx.x;
    const int t = threadIdx.x;
    if (bid < EB) {
        bo_scan(bktTot, sm.c.sBo, sm.c.sW);
        for (int i = t; i < NBUK; i += 256) sm.c.sH[i] = sm.c.sBo[i] + ebaseL[i * EB + bid];
        __syncthreads();
        int base = bid * EPB;
#pragma unroll
        for (int i = 0; i < 32; ++i) {
            int e = base + i * 256 + t;
            if (e < EE) {
                unsigned sv = (unsigned)src[e], d = (unsigned)dst[e];
                int p = atomicAdd(&sm.c.sH[d >> 8], 1);
                ebuf[p] = (sv << 8) | (d & 255u);
            }
        }
    } else {
        gx_tile(x, WpP, bp, h0, sm.asx[0], sm.asx[1], T2N + bid - EB);
    }
}

// ---- K4: cfill (blocks 0..NBUK, with in-block bo scan) || tiles [768,1152) ----
#define T4N 384
__global__ __launch_bounds__(256) void cfill_gx_k(
        const unsigned* __restrict__ ebuf, const int* __restrict__ bktTot,
        int* __restrict__ rowptr, float* __restrict__ dinv,
        int* __restrict__ col, int* __restrict__ bHist,
        const float* __restrict__ x, const _Float16* __restrict__ WpP,
        const float* __restrict__ bp, _Float16* __restrict__ h0) {
    __shared__ union {
        float asx[2][64 * 64];
        struct { int sBo[NBUK + 1]; int sCnt[256]; int sOff[256]; int sC64[64]; int sW[4]; } c;
    } sm;
    const int bid = blockIdx.x;
    const int t = threadIdx.x;
    if (bid < NBUK) {
        bo_scan(bktTot, sm.c.sBo, sm.c.sW);
        const int b = bid;
        const int lo = sm.c.sBo[b], hi = sm.c.sBo[b + 1];
        sm.c.sCnt[t] = 0;
        if (t < 64) sm.c.sC64[t] = 0;
        __syncthreads();
        for (int j = lo + t; j < hi; j += 256)
            atomicAdd(&sm.c.sCnt[ebuf[j] & 255u], 1);
        __syncthreads();
        int v = sm.c.sCnt[t];
        int lane = t & 63, wid = t >> 6;
        int xx = v;
#pragma unroll
        for (int off = 1; off < 64; off <<= 1) {
            int y = __shfl_up(xx, off, 64);
            if (lane >= off) xx += y;
        }
        if (lane == 63) sm.c.sW[wid] = xx;
        __syncthreads();
        if (t == 0) {
            int run = 0;
#pragma unroll
            for (int i = 0; i < 4; ++i) { int c = sm.c.sW[i]; sm.c.sW[i] = run; run += c; }
        }
        __syncthreads();
        int excl = lo + xx - v + sm.c.sW[wid];
        sm.c.sOff[t] = excl;
        int g = (b << 8) + t;
        if (g <= NN) rowptr[g] = excl;
        if (g < NN) {
            dinv[g] = rsqrtf((float)v + 1.0f);
            atomicAdd(&sm.c.sC64[min(v, 63)], 1);
        }
        __syncthreads();
        for (int j = lo + t; j < hi; j += 256) {
            unsigned u = ebuf[j];
            int p = atomicAdd(&sm.c.sOff[u & 255u], 1);
            col[p] = (int)(u >> 8);
        }
        __syncthreads();
        if (t < 64) bHist[t * NBUK + b] = sm.c.sC64[t];
    } else {
        gx_tile(x, WpP, bp, h0, sm.asx[0], sm.asx[1], T2N + T3N + bid - NBUK);
    }
}

// ---- K5: per-degree-row scan of bHist (blocks 0..64) || tiles [1152,1563) ----
#define T5N (XTILES - T2N - T3N - T4N)   // 411
__global__ __launch_bounds__(256) void dscan_gx_k(
        const int* __restrict__ bHist, int* __restrict__ rowPref, int* __restrict__ rowTot,
        const float* __restrict__ x, const _Float16* __restrict__ WpP,
        const float* __restrict__ bp, _Float16* __restrict__ h0) {
    __shared__ union { float asx[2][64 * 64]; int sW[4]; } sm;
    const int bid = blockIdx.x;
    const int t = threadIdx.x;
    if (bid < 64) {
        const int d = bid;
        const int lane = t & 63, wid = t >> 6;
        int i0 = 2 * t, i1 = 2 * t + 1;
        int v0 = (i0 < NBUK) ? bHist[d * NBUK + i0] : 0;
        int v1 = (i1 < NBUK) ? bHist[d * NBUK + i1] : 0;
        int s = v0 + v1;
        int xx = s;
#pragma unroll
        for (int off = 1; off < 64; off <<= 1) {
            int y = __shfl_up(xx, off, 64);
            if (lane >= off) xx += y;
        }
        if (lane == 63) sm.sW[wid] = xx;
        __syncthreads();
        if (t == 0) {
            int run = 0;
#pragma unroll
            for (int i = 0; i < 4; ++i) { int c = sm.sW[i]; sm.sW[i] = run; run += c; }
        }
        __syncthreads();
        int excl = xx - s + sm.sW[wid];
        if (i0 < NBUK) rowPref[d * NBUK + i0] = excl;
        if (i1 < NBUK) rowPref[d * NBUK + i1] = excl + v0;
        if (t == 255) rowTot[d] = excl;   // i0,i1 >= NBUK there -> excl == row total
    } else {
        gx_tile(x, WpP, bp, h0, sm.asx[0], sm.asx[1], T2N + T3N + T4N + bid - 64);
    }
}

// ---------------- MFMA GEMM body (fp16 A) with async-LDS double buffer ----------------
template<int K, int MODE>
__device__ __forceinline__ void mgemm2_body(const _Float16* __restrict__ A,
                                            const _Float16* __restrict__ Bp,
                                            const float* __restrict__ bias,
                                            const float* __restrict__ dinv,
                                            _Float16* __restrict__ C,
                                            _Float16* As, int row0) {
    constexpr int NC = K / 64;
    const int NT = 8;
    const int tid = threadIdx.x;
    const int w = tid >> 6;
    const int L = tid & 63;
    const int q = L >> 4;
    const int l16 = L & 15;

    const int r8 = L >> 3;
    const int scol = ((L & 7) ^ r8) * 8;
    const size_t srow0 = (size_t)min(row0 + w * 8 + r8, NN - 1) * K;
    const size_t srow1 = (size_t)min(row0 + 32 + w * 8 + r8, NN - 1) * K;
    _Float16* lds0a = As + w * 512;
    _Float16* lds0b = As + (4 + w) * 512;
    _Float16* lds1a = As + 4096 + w * 512;
    _Float16* lds1b = As + 4096 + (4 + w) * 512;

    floatx4 acc[NT];
#pragma unroll
    for (int nt = 0; nt < NT; ++nt) acc[nt] = (floatx4){0.f, 0.f, 0.f, 0.f};

    const half8* __restrict__ bp8 = (const half8*)Bp;
    const int rs = l16 & 7;
    const int gsel = (w * 2 + (l16 >> 3)) * 512 + rs * 64;

    async_cp16(A + srow0 + scol, lds0a);
    async_cp16(A + srow1 + scol, lds0b);
    __syncthreads();

    for (int kc = 0; kc < NC; ++kc) {
        if (kc + 1 < NC) {
            if ((kc & 1) == 0) {
                async_cp16(A + srow0 + (kc + 1) * 64 + scol, lds1a);
                async_cp16(A + srow1 + (kc + 1) * 64 + scol, lds1b);
            } else {
                async_cp16(A + srow0 + (kc + 1) * 64 + scol, lds0a);
                async_cp16(A + srow1 + (kc + 1) * 64 + scol, lds0b);
            }
        }
        const _Float16* cur = As + (kc & 1) * 4096;
#pragma unroll
        for (int kk = 0; kk < 2; ++kk) {
            int chunk = kk * 4 + q;
            half8 a = *(const half8*)(cur + gsel + ((chunk ^ rs) * 8));
#pragma unroll
            for (int nt = 0; nt < NT; ++nt) {
                half8 b = bp8[(size_t)((kc * 2 + kk) * NT + nt) * 64 + L];
                acc[nt] = __builtin_amdgcn_mfma_f32_16x16x32_f16(a, b, acc[nt], 0, 0, 0);
            }
        }
        __syncthreads();
    }

#pragma unroll
    for (int r = 0; r < 4; ++r) {
        int row = row0 + w * 16 + q * 4 + r;
        if (row >= NN) continue;
        if (MODE == 0) {
#pragma unroll
            for (int nt = 0; nt < NT; ++nt) {
                int c = nt * 16 + l16;
                C[(size_t)row * HD + c] = (_Float16)fmaxf(acc[nt][r] + bias[c], 0.f);
            }
        } else {
            float dv = dinv[row];
#pragma unroll
            for (int nt = 0; nt < NT; ++nt) {
                int c = nt * 16 + l16;
                C[(size_t)row * HD + c] = (_Float16)(acc[nt][r] * dv);
            }
        }
    }
}

template<int K, int MODE>
__global__ __launch_bounds__(256) void mgemm2_k(const _Float16* __restrict__ A,
                                                const _Float16* __restrict__ Bp,
                                                const float* __restrict__ bias,
                                                const float* __restrict__ dinv,
                                                _Float16* __restrict__ C) {
    __shared__ _Float16 As[2 * 64 * 64];
    mgemm2_body<K, MODE>(A, Bp, bias, dinv, C, As, blockIdx.x * 64);
}

// layer-0 GEMM fused with the counting-sort fill (independent work, saves a dispatch)
__global__ __launch_bounds__(256) void mgemm0_bfill_k(const _Float16* __restrict__ A,
                                                      const _Float16* __restrict__ Bp,
                                                      const float* __restrict__ dinv,
                                                      _Float16* __restrict__ C,
                                                      const int* __restrict__ rowptr,
                                                      const int* __restrict__ rowTot,
                                                      const int* __restrict__ rowPref,
                                                      int* __restrict__ perm) {
    __shared__ _Float16 As[2 * 64 * 64];
    __shared__ int sOff[64];
    if (blockIdx.x < XTILES) {
        mgemm2_body<HD, 1>(A, Bp, nullptr, dinv, C, As, blockIdx.x * 64);
    } else {
        int t = threadIdx.x;
        int b = blockIdx.x - XTILES;
        if (t < 64) {
            int v = rowTot[t];
            int xx = v;
#pragma unroll
            for (int off = 1; off < 64; off <<= 1) {
                int y = __shfl_up(xx, off, 64);
                if (t >= off) xx += y;
            }
            sOff[t] = (xx - v) + rowPref[t * NBUK + b];
        }
        __syncthreads();
        int n = (b << 8) + t;
        if (n < NN) {
            int deg = rowptr[n + 1] - rowptr[n];
            int c = min(deg, 63);
            int p = atomicAdd(&sOff[c], 1);
            perm[p] = n;
        }
    }
}

// ---------------- aggregation + BN + relu + residual (fp16 gather, 8-deep) ----------------
__global__ __launch_bounds__(256) void agg_k(const _Float16* __restrict__ hws,
                                             const _Float16* __restrict__ h_in,
                                             _Float16* __restrict__ h_out,
                                             const float* __restrict__ dinv,
                                             const int* __restrict__ rowptr,
                                             const int* __restrict__ col,
                                             const int* __restrict__ perm,
                                             const float* __restrict__ bcv,
                                             const float* __restrict__ gamma,
                                             const float* __restrict__ beta,
                                             const float* __restrict__ rmean,
                                             const float* __restrict__ rvar,
                                             int residual) {
    int g = blockIdx.x * 16 + (threadIdx.x >> 4);
    if (g >= NN) return;
    int node = perm[g];
    int l = threadIdx.x & 15;
    int f0 = l * 8;

    int lo = rowptr[node], hi = rowptr[node + 1];

    half8 vself = *(const half8*)(hws + (size_t)node * HD + f0);
    half8 hin;
    if (residual) hin = *(const half8*)(h_in + (size_t)node * HD + f0);

    float acc[8];
#pragma unroll
    for (int i = 0; i < 8; ++i) acc[i] = 0.f;

    int j = lo;
    for (; j + 7 < hi; j += 8) {
        half8 v0 = *(const half8*)(hws + (size_t)col[j]     * HD + f0);
        half8 v1 = *(const half8*)(hws + (size_t)col[j + 1] * HD + f0);
        half8 v2 = *(const half8*)(hws + (size_t)col[j + 2] * HD + f0);
        half8 v3 = *(const half8*)(hws + (size_t)col[j + 3] * HD + f0);
        half8 v4 = *(const half8*)(hws + (size_t)col[j + 4] * HD + f0);
        half8 v5 = *(const half8*)(hws + (size_t)col[j + 5] * HD + f0);
        half8 v6 = *(const half8*)(hws + (size_t)col[j + 6] * HD + f0);
        half8 v7 = *(const half8*)(hws + (size_t)col[j + 7] * HD + f0);
#pragma unroll
        for (int i = 0; i < 8; ++i)
            acc[i] += (((float)v0[i] + (float)v1[i]) + ((float)v2[i] + (float)v3[i])) +
                      (((float)v4[i] + (float)v5[i]) + ((float)v6[i] + (float)v7[i]));
    }
    for (; j + 3 < hi; j += 4) {
        half8 v0 = *(const half8*)(hws + (size_t)col[j]     * HD + f0);
        half8 v1 = *(const half8*)(hws + (size_t)col[j + 1] * HD + f0);
        half8 v2 = *(const half8*)(hws + (size_t)col[j + 2] * HD + f0);
        half8 v3 = *(const half8*)(hws + (size_t)col[j + 3] * HD + f0);
#pragma unroll
        for (int i = 0; i < 8; ++i)
            acc[i] += ((float)v0[i] + (float)v1[i]) + ((float)v2[i] + (float)v3[i]);
    }
    for (; j < hi; ++j) {
        half8 v0 = *(const half8*)(hws + (size_t)col[j] * HD + f0);
#pragma unroll
        for (int i = 0; i < 8; ++i) acc[i] += (float)v0[i];
    }
#pragma unroll
    for (int i = 0; i < 8; ++i) acc[i] += (float)vself[i];

    float dv = dinv[node];
    half8 outv;
#pragma unroll
    for (int i = 0; i < 8; ++i) {
        int f = f0 + i;
        float pre = dv * acc[i] + bcv[f];
        float scale = gamma[f] * rsqrtf(rvar[f] + BN_EPS);
        float v = (pre - rmean[f]) * scale + beta[f];
        v = fmaxf(v, 0.f);
        if (residual) v += (float)hin[i];
        outv[i] = (_Float16)v;
    }
    *(half8*)(h_out + (size_t)node * HD + f0) = outv;
}

// ---------------- fused heads ----------------
__global__ __launch_bounds__(256) void heads_k(const _Float16* __restrict__ hfin,
                                               const _Float16* __restrict__ W1P,
                                               const float* __restrict__ b1p,
                                               const float* __restrict__ relW2, const float* __restrict__ relb2,
                                               const float* __restrict__ rsW2,  const float* __restrict__ rsb2,
                                               const float* __restrict__ rlW2,  const float* __restrict__ rlb2,
                                               float* __restrict__ out) {
    __shared__ float Hs[64 * 196];
#define HS(r, c) Hs[(r) * 196 + (c)]
    const int NT = 12;
    const int tid = threadIdx.x;
    const int w = tid >> 6;
    const int L = tid & 63;
    const int q = L >> 4;
    const int l16 = L & 15;
    const int row0 = blockIdx.x * 64 + w * 16;

    floatx4 acc[NT];
#pragma unroll
    for (int nt = 0; nt < NT; ++nt) acc[nt] = (floatx4){0.f, 0.f, 0.f, 0.f};

    const half8* __restrict__ bp8 = (const half8*)W1P;
    const half8 hz = {(_Float16)0, (_Float16)0, (_Float16)0, (_Float16)0,
                      (_Float16)0, (_Float16)0, (_Float16)0, (_Float16)0};
    const int r0 = row0 + l16;

#pragma unroll
    for (int kc = 0; kc < HD / 32; ++kc) {
        half8 a = (r0 < NN) ? *(const half8*)(hfin + (size_t)r0 * HD + kc * 32 + q * 8) : hz;
#pragma unroll
        for (int nt = 0; nt < NT; ++nt) {
            half8 b = bp8[(size_t)(kc * NT + nt) * 64 + L];
            acc[nt] = __builtin_amdgcn_mfma_f32_16x16x32_f16(a, b, acc[nt], 0, 0, 0);
        }
    }

#pragma unroll
    for (int nt = 0; nt < NT; ++nt) {
        int c = nt * 16 + l16;
        float bb = b1p[c];
#pragma unroll
        for (int r = 0; r < 4; ++r)
            HS(w * 16 + q * 4 + r, c) = fmaxf(acc[nt][r] + bb, 0.f);
    }
    __syncthreads();

    for (int t = tid; t < 64 * 6; t += 256) {
        int row = t & 63;
        int o = t >> 6;
        int grow = blockIdx.x * 64 + row;
        if (grow >= NN) continue;
        if (o == 0) {
            float s = 0.f;
#pragma unroll
            for (int jj = 0; jj < 64; ++jj) s += HS(row, 64 + jj) * rsW2[jj];
            out[grow] = 1.f / (1.f + expf(-(s + rsb2[0])));
        } else if (o <= 4) {
            int c = o - 1;
            float s = 0.f;
#pragma unroll
            for (int jj = 0; jj < 64; ++jj) s += HS(row, 128 + jj) * rlW2[jj * NRL + c];
            out[NN + (size_t)grow * NRL + c] = s + rlb2[c];
        } else {
            float s = 0.f;
#pragma unroll
            for (int jj = 0; jj < 64; ++jj) s += HS(row, jj) * relW2[jj];
            out[NN * (1 + NRL) + grow] = 1.f / (1.f + expf(-(s + relb2[0])));
        }
    }
#undef HS
}

extern "C" void kernel_launch(void* const* d_in, const int* in_sizes, int n_in,
                              void* d_out, int out_size, void* d_ws, size_t ws_size,
                              hipStream_t stream) {
    const float* x     = (const float*)d_in[0];
    const int*   ei    = (const int*)d_in[1];
    const float* Wp    = (const float*)d_in[2];
    const float* bp    = (const float*)d_in[3];
    const float* Wc    = (const float*)d_in[4];
    const float* bc    = (const float*)d_in[5];
    const float* gamma = (const float*)d_in[6];
    const float* beta  = (const float*)d_in[7];
    const float* rmean = (const float*)d_in[8];
    const float* rvar  = (const float*)d_in[9];
    const float* relW1 = (const float*)d_in[10];
    const float* relb1 = (const float*)d_in[11];
    const float* relW2 = (const float*)d_in[12];
    const float* relb2 = (const float*)d_in[13];
    const float* rsW1  = (const float*)d_in[14];
    const float* rsb1  = (const float*)d_in[15];
    const float* rsW2  = (const float*)d_in[16];
    const float* rsb2  = (const float*)d_in[17];
    const float* rlW1  = (const float*)d_in[18];
    const float* rlb1  = (const float*)d_in[19];
    const float* rlW2  = (const float*)d_in[20];
    const float* rlb2  = (const float*)d_in[21];
    float* out = (float*)d_out;

    char* w = (char*)d_ws;
    _Float16* h0  = (_Float16*)w; w += (size_t)NN * HD * 2;
    _Float16* h1  = (_Float16*)w; w += (size_t)NN * HD * 2;
    _Float16* hws = (_Float16*)w; w += (size_t)NN * HD * 2;
    _Float16* WpP = (_Float16*)w; w += (size_t)DIN * HD * 2;
    _Float16* WcP = (_Float16*)w; w += (size_t)3 * HD * HD * 2;
    _Float16* W1P = (_Float16*)w; w += (size_t)HD * 192 * 2;
    float* b1p    = (float*)w;    w += 256 * 4;
    float* dinv   = (float*)w;    w += (size_t)NN * 4;
    int* rowptr   = (int*)w;      w += (size_t)(NN + 4) * 4;
    int* col      = (int*)w;      w += (size_t)EE * 4;
    int* perm     = (int*)w;      w += (size_t)NN * 4;
    int* bHist    = (int*)w;      w += (size_t)64 * NBUK * 4;
    int* rowPref  = (int*)w;      w += (size_t)64 * NBUK * 4;
    int* rowTot   = (int*)w;      w += 64 * 4;
    int* eHist    = (int*)w;      w += (size_t)NBUK * EB * 4;
    int* ebaseL   = (int*)w;      w += (size_t)(NBUK * EB + 4) * 4;
    int* bktTot   = (int*)w;      w += (size_t)(NBUK + 4) * 4;
    w = (char*)(((size_t)w + 255) & ~(size_t)255);
    unsigned* ebuf = (unsigned*)w; w += (size_t)EE * 4;

    const int* srcIdx = ei;
    const int* dstIdx = ei + EE;

    // front-end: CSR chain (phase per launch) || pack + input-projection tile slices.
    hist_pack_k<<<EB + PKB, 256, 0, stream>>>(dstIdx, eHist, Wp, Wc,
                                              relW1, rsW1, rlW1, relb1, rsb1, rlb1,
                                              WpP, WcP, W1P, b1p);
    escan_gx_k<<<NBUK + T2N, 256, 0, stream>>>(eHist, ebaseL, bktTot, x, WpP, bp, h0);
    ebfill_gx_k<<<EB + T3N, 256, 0, stream>>>(srcIdx, dstIdx, ebaseL, bktTot, ebuf,
                                              x, WpP, bp, h0);
    cfill_gx_k<<<NBUK + T4N, 256, 0, stream>>>(ebuf, bktTot, rowptr, dinv, col, bHist,
                                               x, WpP, bp, h0);
    dscan_gx_k<<<64 + T5N, 256, 0, stream>>>(bHist, rowPref, rowTot, x, WpP, bp, h0);

    const int aggGrid = (NN + 15) / 16;
    const int gemmGrid = (NN + 63) / 64;

    // layer 0 GEMM || counting-sort fill
    mgemm0_bfill_k<<<XTILES + NBUK, 256, 0, stream>>>(h0, WcP + 0 * HD * HD, dinv, hws,
                                                      rowptr, rowTot, rowPref, perm);
    agg_k<<<aggGrid, 256, 0, stream>>>(hws, h0, h1, dinv, rowptr, col, perm,
                                       bc + 0 * HD, gamma + 0 * HD, beta + 0 * HD,
                                       rmean + 0 * HD, rvar + 0 * HD, 0);
    // layer 1
    mgemm2_k<HD, 1><<<gemmGrid, 256, 0, stream>>>(h1, WcP + 1 * HD * HD, nullptr, dinv, hws);
    agg_k<<<aggGrid, 256, 0, stream>>>(hws, h1, h0, dinv, rowptr, col, perm,
                                       bc + 1 * HD, gamma + 1 * HD, beta + 1 * HD,
                                       rmean + 1 * HD, rvar + 1 * HD, 1);
    // layer 2
    mgemm2_k<HD, 1><<<gemmGrid, 256, 0, stream>>>(h0, WcP + 2 * HD * HD, nullptr, dinv, hws);
    agg_k<<<aggGrid, 256, 0, stream>>>(hws, h0, h1, dinv, rowptr, col, perm,
                                       bc + 2 * HD, gamma + 2 * HD, beta + 2 * HD,
                                       rmean + 2 * HD, rvar + 2 * HD, 1);

    // heads
    heads_k<<<(NN + 63) / 64, 256, 0, stream>>>(h1, W1P, b1p, relW2, relb2, rsW2, rsb2, rlW2, rlb2, out);
}